// Round 3
// baseline (1898.454 us; speedup 1.0000x reference)
//
#include <hip/hip_runtime.h>

#define TDS 512
#define NBATCH 256

// packed f16 pair type
typedef _Float16 h2 __attribute__((ext_vector_type(2)));

__device__ __forceinline__ unsigned int pack2(float lo, float hi) {
    h2 v;
    v.x = (_Float16)lo;
    v.y = (_Float16)hi;
    return __builtin_bit_cast(unsigned int, v);
}
__device__ __forceinline__ h2 uph(unsigned int u) {
    return __builtin_bit_cast(h2, u);
}

#if __has_builtin(__builtin_amdgcn_fdot2)
__device__ __forceinline__ float fdot2(h2 w, h2 x, float acc) {
    return __builtin_amdgcn_fdot2(w, x, acc, false);
}
#else
__device__ __forceinline__ float fdot2(h2 w, h2 x, float acc) {
    return fmaf((float)w.x, (float)x.x, fmaf((float)w.y, (float)x.y, acc));
}
#endif

__device__ __forceinline__ float fast_rcp(float x) {
#if __has_builtin(__builtin_amdgcn_rcpf)
    return __builtin_amdgcn_rcpf(x);
#else
    return 1.0f / x;
#endif
}

// tanh(x) = 1 - 2/(exp(2x)+1); exact at +-inf, ~1e-7 abs error elsewhere
__device__ __forceinline__ float fast_tanh(float x) {
    return 1.0f - 2.0f * fast_rcp(1.0f + __expf(2.0f * x));
}
__device__ __forceinline__ float fast_sigmoid(float x) {
    return fast_rcp(1.0f + __expf(-x));
}

// Output element offsets (float32 elements)
#define KEYS_OFF 0u
#define PRS_OFF  262144u
#define HS_OFF   786432u
#define TM_OFF   67895296u

// packed-h double buffer geometry: stride 72 uints per k-chunk (bank-conflict pad)
#define HP_CHUNK 72
#define HP_BUF   (4 * HP_CHUNK)   // 288 uints per buffer

__device__ __forceinline__ void flush_window(
    float* __restrict__ g_out, int b, int tid, int w,
    const float* __restrict__ lds_hst,
    const float (*__restrict__ lds_kst)[2],
    const float (*__restrict__ lds_pst)[4])
{
    const int tbase = w * 8;
    float h[8];
#pragma unroll
    for (int s = 0; s < 8; ++s) h[s] = lds_hst[s * TDS + tid];
    float4* dst = (float4*)(g_out + HS_OFF + (unsigned)b * 262144u + (unsigned)tid * 512u + (unsigned)tbase);
    dst[0] = make_float4(h[0], h[1], h[2], h[3]);
    dst[1] = make_float4(h[4], h[5], h[6], h[7]);

    if (tid < 2) {
        float k[8];
#pragma unroll
        for (int s = 0; s < 8; ++s) k[s] = lds_kst[s][tid];
        float4* kd = (float4*)(g_out + KEYS_OFF + (unsigned)b * 1024u + (unsigned)tid * 512u + (unsigned)tbase);
        kd[0] = make_float4(k[0], k[1], k[2], k[3]);
        kd[1] = make_float4(k[4], k[5], k[6], k[7]);
    } else if (tid < 6) {
        const int o = tid - 2;
        float p[8];
#pragma unroll
        for (int s = 0; s < 8; ++s) p[s] = lds_pst[s][o];
        float4* pd = (float4*)(g_out + PRS_OFF + (unsigned)b * 2048u + (unsigned)o * 512u + (unsigned)tbase);
        pd[0] = make_float4(p[0], p[1], p[2], p[3]);
        pd[1] = make_float4(p[4], p[5], p[6], p[7]);
    }
}

__global__ __launch_bounds__(TDS, 1) void rnn_att_kernel(
    const float* __restrict__ g_inputs,  // (256, 8, 512) f32
    const float* __restrict__ g_Win,     // (512, 6)
    const float* __restrict__ g_bin,     // (512,)
    const float* __restrict__ g_Wrec,    // (512, 512)
    const float* __restrict__ g_brec,    // (512,)
    const float* __restrict__ g_Wkey,    // (2, 512)
    const float* __restrict__ g_bkey,    // (2,)
    float* __restrict__ g_out)
{
    // LDS: 128K weight tier + 2.25K packed-h dbuf + 16K staging + small ≈ 146.6 KB
    __shared__ __attribute__((aligned(16))) unsigned int lds_w[64][TDS];     // f16-pair weight tier
    __shared__ __attribute__((aligned(16))) unsigned int lds_hp[2 * HP_BUF]; // packed f16 h dbuf, padded
    __shared__ __attribute__((aligned(16))) float lds_hst[8 * TDS];          // hs staging [s][row]
    __shared__ __attribute__((aligned(16))) float lds_ksum[2][16];
    __shared__ float lds_kst[8][2];
    __shared__ float lds_pst[8][4];

    const int tid = threadIdx.x;
    const int b = blockIdx.x;
    const int kc = tid & 3;        // k-chunk (128 k = 64 pairs each)
    const int rg = tid >> 2;       // row group (4 rows each)
    const int r_out = tid;         // this thread's output row

    // ---------------- init: load weights (f32 source) as f16 pairs ----------------
    // thread: rows 4rg..4rg+3, chunk-pairs 0..63 per row.
    // pairs 0..47 of each row in regs (192 uints), pairs 48..63 in LDS (64 uints).
    unsigned int wreg[192];
#pragma unroll
    for (int i = 0; i < 4; ++i) {
        const int r = (rg << 2) + i;
        const float4* src = (const float4*)(g_Wrec + r * 512 + kc * 128);
#pragma unroll
        for (int g = 0; g < 16; ++g) {
            float4 f0 = src[2 * g];
            float4 f1 = src[2 * g + 1];
            unsigned int u0 = pack2(f0.x, f0.y);
            unsigned int u1 = pack2(f0.z, f0.w);
            unsigned int u2 = pack2(f1.x, f1.y);
            unsigned int u3 = pack2(f1.z, f1.w);
            if (g < 12) {
                wreg[i * 48 + g * 4 + 0] = u0;
                wreg[i * 48 + g * 4 + 1] = u1;
                wreg[i * 48 + g * 4 + 2] = u2;
                wreg[i * 48 + g * 4 + 3] = u3;
            } else {
                const int pbase = i * 16 + (g - 12) * 4;
                lds_w[pbase + 0][tid] = u0;
                lds_w[pbase + 1][tid] = u1;
                lds_w[pbase + 2][tid] = u2;
                lds_w[pbase + 3][tid] = u3;
            }
        }
    }

    float win[6];
#pragma unroll
    for (int j = 0; j < 6; ++j) win[j] = g_Win[r_out * 6 + j];
    const float bias = g_bin[r_out] + g_brec[r_out];
    const float wk0 = g_Wkey[r_out];
    const float wk1 = g_Wkey[512 + r_out];
    const float bk0 = g_bkey[0];
    const float bk1 = g_bkey[1];

    // zero both packed-h buffers (h0 = 0): 576 uints
    lds_hp[tid] = 0u;
    if (tid < 2 * HP_BUF - TDS) lds_hp[TDS + tid] = 0u;

    // tm_modified = inputs[:, 6:8, :] (f32 copy, 4 KB per batch)
    if (tid < 256) {
        const float4* s = (const float4*)(g_inputs + b * 4096 + 3072);
        float4* d = (float4*)(g_out + TM_OFF + (unsigned)b * 1024u);
        d[tid] = s[tid];
    }
    __syncthreads();

    // ---------------- sequential scan ----------------
    const float* gin = g_inputs + b * 4096;
    float key_pre = 1.0f;
    float xv[8];   // inputs for current step t (valid for t >= 1)

    for (int t = 0; t < 512; ++t) {
        const int s = t & 7;
        if (s == 0 && t > 0) {
            __syncthreads();                       // staging writes (incl. kst) visible
            flush_window(g_out, b, tid, (t >> 3) - 1, lds_hst, lds_kst, lds_pst);
            __syncthreads();                       // flush reads done before new-window writes
        }

        // prefetch inputs for step t+1 (uniform address, no loop-state dependence)
        float xn[8];
        {
            const int tn = (t < 511) ? t + 1 : 511;
#pragma unroll
            for (int j = 0; j < 8; ++j) xn[j] = gin[512 * j + tn];
        }

        float h_new = 0.0f, p0 = 0.0f, p1 = 0.0f, p2 = 0.0f, p3 = 0.0f;
        if (t > 0) {
            float x0 = xv[0], x1 = xv[1], x2 = xv[2], x3 = xv[3];
            float x4 = xv[4], x5 = xv[5], x6 = xv[6], x7 = xv[7];
            float as0 = x2 * key_pre + x4 * (1.0f - key_pre);
            float as1 = x3 * key_pre + x5 * (1.0f - key_pre);
            float wd = bias;
            wd = fmaf(x0, win[0], wd);
            wd = fmaf(x1, win[1], wd);
            wd = fmaf(as0, win[2], wd);
            wd = fmaf(as1, win[3], wd);
            wd = fmaf(x6, win[4], wd);
            wd = fmaf(x7, win[5], wd);
            {
                float q0 = (x6 - x0) / (0.15f * x0);
                float q1 = (x6 - x1) / (0.15f * x1);
                float q2 = (x7 - as0) / (0.15f * as0);
                float q3 = (x7 - as1) / (0.15f * as1);
                p0 = q0 * q0; p1 = q1 * q1; p2 = q2 * q2; p3 = q3 * q3;
                if (x6 == 0.0f) { p0 = 0.0f; p1 = 0.0f; }
                if (x7 == 0.0f) { p2 = 0.0f; p3 = 0.0f; }
            }
            // matvec: rows 4rg..4rg+3, k-chunk kc — packed f16 h × f16-pair weights, v_dot2_f32_f16
            const unsigned int* hb = lds_hp + ((t - 1) & 1) * HP_BUF + kc * HP_CHUNK;
            float a[4] = {0.0f, 0.0f, 0.0f, 0.0f};
            // register tier: chunk-pairs 0..47 per row
#pragma unroll
            for (int c = 0; c < 12; ++c) {            // c-th uint4 = chunk-pairs 4c..4c+3
                uint4 hu = ((const uint4*)hb)[c];
                h2 x0h = uph(hu.x), x1h = uph(hu.y), x2h = uph(hu.z), x3h = uph(hu.w);
#pragma unroll
                for (int i = 0; i < 4; ++i) {
                    a[i] = fdot2(uph(wreg[i * 48 + 4 * c + 0]), x0h, a[i]);
                    a[i] = fdot2(uph(wreg[i * 48 + 4 * c + 1]), x1h, a[i]);
                    a[i] = fdot2(uph(wreg[i * 48 + 4 * c + 2]), x2h, a[i]);
                    a[i] = fdot2(uph(wreg[i * 48 + 4 * c + 3]), x3h, a[i]);
                }
            }
            // LDS tier: chunk-pairs 48..63 per row
#pragma unroll
            for (int c = 0; c < 4; ++c) {
                uint4 hu = ((const uint4*)(hb + 48))[c];
                h2 x0h = uph(hu.x), x1h = uph(hu.y), x2h = uph(hu.z), x3h = uph(hu.w);
#pragma unroll
                for (int i = 0; i < 4; ++i) {
                    a[i] = fdot2(uph(lds_w[i * 16 + 4 * c + 0][tid]), x0h, a[i]);
                    a[i] = fdot2(uph(lds_w[i * 16 + 4 * c + 1][tid]), x1h, a[i]);
                    a[i] = fdot2(uph(lds_w[i * 16 + 4 * c + 2][tid]), x2h, a[i]);
                    a[i] = fdot2(uph(lds_w[i * 16 + 4 * c + 3][tid]), x3h, a[i]);
                }
            }
            // reduce over the 4 k-chunks (lanes kc=0..3 adjacent in-wave)
#pragma unroll
            for (int i = 0; i < 4; ++i) {
                a[i] += __shfl_xor(a[i], 1, 64);
                a[i] += __shfl_xor(a[i], 2, 64);
            }
            float rsum = a[0];
            if (kc == 1) rsum = a[1];
            if (kc == 2) rsum = a[2];
            if (kc == 3) rsum = a[3];
            h_new = fast_tanh(rsum + wd);

            // write packed h pair (rows 2p, 2p+1) into next buffer; even lane writes
            float h_other = __shfl_xor(h_new, 1, 64);
            if ((tid & 1) == 0) {
                const int p = tid >> 1;
                lds_hp[(t & 1) * HP_BUF + (p >> 6) * HP_CHUNK + (p & 63)] = pack2(h_new, h_other);
            }

            // key partial sums (wave butterfly), lane0 of each wave -> LDS
            float kp0 = h_new * wk0, kp1 = h_new * wk1;
#pragma unroll
            for (int m = 1; m < 64; m <<= 1) {
                kp0 += __shfl_xor(kp0, m, 64);
                kp1 += __shfl_xor(kp1, m, 64);
            }
            if ((tid & 63) == 0) {
                lds_ksum[t & 1][(tid >> 6) * 2 + 0] = kp0;
                lds_ksum[t & 1][(tid >> 6) * 2 + 1] = kp1;
            }
            if (tid == 0) {
                lds_pst[s][0] = p0; lds_pst[s][1] = p1;
                lds_pst[s][2] = p2; lds_pst[s][3] = p3;
            }
        } else {
            if (tid == 0) {
                lds_pst[s][0] = 0.0f; lds_pst[s][1] = 0.0f;
                lds_pst[s][2] = 0.0f; lds_pst[s][3] = 0.0f;
            }
        }
        lds_hst[s * TDS + r_out] = h_new;   // t=0 stages zeros (f32, full precision)

        __syncthreads();  // h buffer + ksum + staging visible

        float k0 = 0.0f, k1 = 0.0f;
        if (t > 0) {
            // 16 contiguous floats: wave w wrote slots 2w, 2w+1
            const float4* ks = (const float4*)&lds_ksum[t & 1][0];
            float4 v0 = ks[0], v1 = ks[1], v2 = ks[2], v3 = ks[3];
            float s0 = ((v0.x + v1.x) + (v2.x + v3.x)) + ((v0.z + v1.z) + (v2.z + v3.z));
            float s1 = ((v0.y + v1.y) + (v2.y + v3.y)) + ((v0.w + v1.w) + (v2.w + v3.w));
            k0 = fast_sigmoid(s0 + bk0);
            k1 = fast_sigmoid(s1 + bk1);
            key_pre = k0;
        }
        if (tid == 0) { lds_kst[s][0] = k0; lds_kst[s][1] = k1; }

        // rotate input pipeline
#pragma unroll
        for (int j = 0; j < 8; ++j) xv[j] = xn[j];
    }

    __syncthreads();
    flush_window(g_out, b, tid, 63, lds_hst, lds_kst, lds_pst);
}

extern "C" void kernel_launch(void* const* d_in, const int* in_sizes, int n_in,
                              void* d_out, int out_size, void* d_ws, size_t ws_size,
                              hipStream_t stream) {
    rnn_att_kernel<<<dim3(NBATCH), dim3(TDS), 0, stream>>>(
        (const float*)d_in[0],
        (const float*)d_in[1],
        (const float*)d_in[2],
        (const float*)d_in[3],
        (const float*)d_in[4],
        (const float*)d_in[5],
        (const float*)d_in[6],
        (float*)d_out);
}